// Round 1
// 1626.839 us; speedup vs baseline: 1.2651x; 1.2651x over previous
//
#include <hip/hip_runtime.h>
#include <hip/hip_bf16.h>
#include <stdint.h>

// MHSA with RPE on gfx950 — fp32 in/out per the reference.
// v2: all GEMMs use global_load_lds(16B) staging (m97 pattern) with fully
// padded operands (no masking, no tail): K padded 784->800, weights padded
// to 896x800, per-head mats padded to 224x224 with zeroed pads.
// Qt (hi/lo) and Vt are produced by OPERAND-SWAPPED projection GEMMs
// (A=weight, B=X) so their epilogue writes are token-contiguous (coalesced)
// instead of 448B-strided scatter.  softmax emits bf16 P directly.

using bf16 = __hip_bfloat16;
typedef __bf16   bf16x8 __attribute__((ext_vector_type(8)));
typedef __bf16   bf16x4 __attribute__((ext_vector_type(4)));
typedef float    f32x4  __attribute__((ext_vector_type(4)));

#define PADN 224
#define MATE (PADN*PADN)        // 50176 elems per padded head-matrix
#define MATB2 (MATE*2)          // 100,352 bytes (bf16)
#define WROWS 896               // padded weight rows (7*128)
#define KPAD 800                // padded K dim (25 * 32)
#define XROWB (KPAD*2)          // 1600 B per padded bf16 row

// async 16B global->LDS. lds must be wave-uniform; g is per-lane.
__device__ __forceinline__ void gload16(void* lds, const void* g) {
  __builtin_amdgcn_global_load_lds(
      (const __attribute__((address_space(1))) void*)g,
      (__attribute__((address_space(3))) void*)lds, 16, 0, 0);
}

// One BK=32 step: 4 A-frags + 4 B-frags (ds_read_b128) + 16 MFMA.
// A-frag: lane holds A[m=lane&15][k=(lane>>4)*8+j]; B identical with n.
__device__ __forceinline__ void mfma_tiles(const char* bufA, const char* bufB,
                                           f32x4 (&acc)[4][4], int wr, int wc,
                                           int lane) {
  const int q = lane >> 4, c = lane & 15;
  bf16x8 a[4], b[4];
#pragma unroll
  for (int i = 0; i < 4; ++i)
    a[i] = *(const bf16x8*)(bufA + ((wr * 64 + i * 16 + c) << 6) + (q << 4));
#pragma unroll
  for (int j = 0; j < 4; ++j)
    b[j] = *(const bf16x8*)(bufB + ((wc * 64 + j * 16 + c) << 6) + (q << 4));
#pragma unroll
  for (int i = 0; i < 4; ++i)
#pragma unroll
    for (int j = 0; j < 4; ++j)
      acc[i][j] = __builtin_amdgcn_mfma_f32_16x16x32_bf16(a[i], b[j], acc[i][j], 0, 0, 0);
}

// ---------------- projection GEMMs, all padded / unmasked -------------------
// EPI 0: Q   = NT(XB, WqB) -> Q[n][d] bf16           grid (M/128, 7)
// EPI 1: K   = NT(XB, WkB) -> K[m][d] bf16           grid (M/128, 7)
// EPI 2: Qt  = NT(WqB, XB) -> Qth/Qtl [d][n] bf16    grid (7, M/128)  (swapped)
// EPI 3: Vt  = NT(WvB, XB) -> Vt [d][m] bf16         grid (7, M/128)  (swapped)
// EPI 4: out = NT(Ob, WoB) -> fp32 [row][784]        grid (M/128, 7)
template <int EPI>
__global__ __launch_bounds__(256) void gemm_proj(
    const bf16* __restrict__ A, const bf16* __restrict__ B,
    const float* __restrict__ bias, bf16* __restrict__ d1,
    bf16* __restrict__ d2, float* __restrict__ dF, int M) {
  __shared__ __align__(16) char smem[16384];
  char* bufA = smem;
  char* bufB = smem + 8192;
  const int tid = threadIdx.x, lane = tid & 63, wave = tid >> 6;
  const int wr = wave >> 1, wc = wave & 1;
  const int m0 = blockIdx.x * 128, n0 = blockIdx.y * 128;

  f32x4 acc[4][4] = {};

  // staging coords: wave covers rows [wave*32, wave*32+31], two 1KB slots.
  const int r0 = wave * 32 + (lane >> 2);
  const int bo = (lane & 3) << 4;
  const char* gA = (const char*)A + (size_t)(m0 + r0) * XROWB + bo;
  const char* gB = (const char*)B + (size_t)(n0 + r0) * XROWB + bo;
  char* lA = bufA + wave * 2048;
  char* lB = bufB + wave * 2048;

  for (int kc = 0; kc < 25; ++kc) {
    const int ko = kc * 64;
    gload16(lA,        gA + ko);
    gload16(lA + 1024, gA + 16 * XROWB + ko);
    gload16(lB,        gB + ko);
    gload16(lB + 1024, gB + 16 * XROWB + ko);
    __syncthreads();
    mfma_tiles(bufA, bufB, acc, wr, wc, lane);
    __syncthreads();
  }

  // Epilogue.  C/D layout: col = lane&15, row = (lane>>4)*4 + reg  [m89].
  const int q = lane >> 4, c = lane & 15;
  if (EPI == 0 || EPI == 1) {            // rows = tokens, cols = features
#pragma unroll
    for (int j = 0; j < 4; ++j) {
      const int col = n0 + wc * 64 + j * 16 + c;
      if (col >= 784) continue;
      const float bs = bias[col];
      const int hh = col / 196, dd = col - hh * 196;
#pragma unroll
      for (int i = 0; i < 4; ++i)
#pragma unroll
        for (int r = 0; r < 4; ++r) {
          const int row = m0 + wr * 64 + i * 16 + q * 4 + r;
          const int b = row / 196, n = row - b * 196;
          d1[(size_t)(b * 4 + hh) * MATE + (size_t)n * PADN + dd] =
              __float2bfloat16(acc[i][j][r] + bs);
        }
    }
  } else if (EPI == 4) {                 // fp32 final output
#pragma unroll
    for (int j = 0; j < 4; ++j) {
      const int col = n0 + wc * 64 + j * 16 + c;
      if (col >= 784) continue;
      const float bs = bias[col];
#pragma unroll
      for (int i = 0; i < 4; ++i)
#pragma unroll
        for (int r = 0; r < 4; ++r) {
          const int row = m0 + wr * 64 + i * 16 + q * 4 + r;
          dF[(size_t)row * 784 + col] = acc[i][j][r] + bs;
        }
    }
  } else {                               // swapped: rows = features, cols = tokens
#pragma unroll
    for (int i = 0; i < 4; ++i)
#pragma unroll
      for (int r = 0; r < 4; ++r) {
        const int row = m0 + wr * 64 + i * 16 + q * 4 + r;  // feature index
        if (row >= 784) continue;
        const float bs = bias[row];
        const int hh = row / 196, dd = row - hh * 196;
#pragma unroll
        for (int j = 0; j < 4; ++j) {
          const int col = n0 + wc * 64 + j * 16 + c;        // token index
          const int b = col / 196, n = col - b * 196;
          const float v = acc[i][j][r] + bs;
          const size_t o = (size_t)(b * 4 + hh) * MATE + (size_t)dd * PADN + n;
          const bf16 hv = __float2bfloat16(v);
          d1[o] = hv;                                       // coalesced in n
          if (EPI == 2) d2[o] = __float2bfloat16(v - __bfloat162float(hv));
        }
      }
  }
}

// ------ scores: S = (Q K^T)/14 + CPh*Qth^T + CPh*Qtl^T + CPl*Qth^T ----------
__global__ __launch_bounds__(256) void attn_score(
    const bf16* __restrict__ Q, const bf16* __restrict__ K,
    const bf16* __restrict__ CPh, const bf16* __restrict__ CPl,
    const bf16* __restrict__ Qth, const bf16* __restrict__ Qtl,
    float* __restrict__ S) {
  __shared__ __align__(16) char smem[24576];
  char* bufA = smem;
  char* bufB = smem + 8192;
  char* bufC = smem + 16384;
  const int tid = threadIdx.x, lane = tid & 63, wave = tid >> 6;
  const int wr = wave >> 1, wc = wave & 1;
  const int bh = blockIdx.z, h = bh & 3;
  const int m0 = blockIdx.x * 128, n0 = blockIdx.y * 128;

  f32x4 acc[4][4] = {};

  const int r0 = wave * 32 + (lane >> 2);
  const int bo = (lane & 3) << 4;
  const size_t la = (size_t)(m0 + r0) * 448 + bo;
  const size_t lb = (size_t)(n0 + r0) * 448 + bo;
  const size_t bhB = (size_t)bh * MATB2, hB = (size_t)h * MATB2;
  const char* aQ  = (const char*)Q   + bhB + la;
  const char* aK  = (const char*)K   + bhB + lb;
  const char* aCh = (const char*)CPh + hB  + la;
  const char* aCl = (const char*)CPl + hB  + la;
  const char* aTh = (const char*)Qth + bhB + lb;
  const char* aTl = (const char*)Qtl + bhB + lb;
  char* lA = bufA + wave * 2048;
  char* lB = bufB + wave * 2048;
  char* lC = bufC + wave * 2048;

  for (int kc = 0; kc < 7; ++kc) {       // pass 1: QK^T
    const int ko = kc * 64;
    gload16(lA, aQ + ko); gload16(lA + 1024, aQ + 16 * 448 + ko);
    gload16(lB, aK + ko); gload16(lB + 1024, aK + 16 * 448 + ko);
    __syncthreads();
    mfma_tiles(bufA, bufB, acc, wr, wc, lane);
    __syncthreads();
  }
#pragma unroll
  for (int i = 0; i < 4; ++i)
#pragma unroll
    for (int j = 0; j < 4; ++j) acc[i][j] = acc[i][j] * (1.0f / 14.0f);

  for (int kc = 0; kc < 7; ++kc) {       // passes 2+3: CPh*(Qth, Qtl)
    const int ko = kc * 64;
    gload16(lA, aCh + ko); gload16(lA + 1024, aCh + 16 * 448 + ko);
    gload16(lB, aTh + ko); gload16(lB + 1024, aTh + 16 * 448 + ko);
    gload16(lC, aTl + ko); gload16(lC + 1024, aTl + 16 * 448 + ko);
    __syncthreads();
    mfma_tiles(bufA, bufB, acc, wr, wc, lane);
    mfma_tiles(bufA, bufC, acc, wr, wc, lane);
    __syncthreads();
  }

  for (int kc = 0; kc < 7; ++kc) {       // pass 4: CPl*Qth
    const int ko = kc * 64;
    gload16(lA, aCl + ko); gload16(lA + 1024, aCl + 16 * 448 + ko);
    gload16(lB, aTh + ko); gload16(lB + 1024, aTh + 16 * 448 + ko);
    __syncthreads();
    mfma_tiles(bufA, bufB, acc, wr, wc, lane);
    __syncthreads();
  }

  float* Sb = S + (size_t)bh * MATE;
  const int q = lane >> 4, c = lane & 15;
#pragma unroll
  for (int i = 0; i < 4; ++i)
#pragma unroll
    for (int j = 0; j < 4; ++j)
#pragma unroll
      for (int r = 0; r < 4; ++r) {
        const int row = m0 + wr * 64 + i * 16 + q * 4 + r;
        const int col = n0 + wc * 64 + j * 16 + c;
        if (row < 196 && col < PADN) Sb[(size_t)row * PADN + col] = acc[i][j][r];
      }
}

// ------------- softmax over cols; emit bf16 P with zeroed pads --------------
__global__ __launch_bounds__(256) void softmax_k(const float* __restrict__ S,
                                                 bf16* __restrict__ P) {
  const int bh = blockIdx.y;
  const int row = blockIdx.x * 4 + (threadIdx.x >> 6);   // 0..223
  const int lane = threadIdx.x & 63;
  bf16* Pr = P + (size_t)bh * MATE + (size_t)row * PADN;
  if (row >= 196) {
#pragma unroll
    for (int k = 0; k < 4; ++k) {
      const int m = lane + k * 64;
      if (m < PADN) Pr[m] = __float2bfloat16(0.f);
    }
    return;
  }
  const float* Sr = S + (size_t)bh * MATE + (size_t)row * PADN;
  float v[4];
  float mx = -1e30f;
#pragma unroll
  for (int k = 0; k < 4; ++k) {
    const int m = lane + k * 64;
    v[k] = (m < 196) ? Sr[m] : -1e30f;
    mx = fmaxf(mx, v[k]);
  }
#pragma unroll
  for (int off = 32; off; off >>= 1) mx = fmaxf(mx, __shfl_xor(mx, off));
  float s = 0.f;
#pragma unroll
  for (int k = 0; k < 4; ++k) {
    const int m = lane + k * 64;
    v[k] = (m < 196) ? __expf(v[k] - mx) : 0.f;
    s += v[k];
  }
#pragma unroll
  for (int off = 32; off; off >>= 1) s += __shfl_xor(s, off);
  const float inv = 1.0f / s;
#pragma unroll
  for (int k = 0; k < 4; ++k) {
    const int m = lane + k * 64;
    if (m < PADN) Pr[m] = __float2bfloat16((m < 196) ? v[k] * inv : 0.f);
  }
}

// -------------------- O[n,d] = sum_m P[n,m] Vt[d,m] ------------------------
__global__ __launch_bounds__(256) void attn_pv(const bf16* __restrict__ P,
                                               const bf16* __restrict__ Vt,
                                               bf16* __restrict__ O) {
  __shared__ __align__(16) char smem[16384];
  char* bufA = smem;
  char* bufB = smem + 8192;
  const int tid = threadIdx.x, lane = tid & 63, wave = tid >> 6;
  const int wr = wave >> 1, wc = wave & 1;
  const int bh = blockIdx.z;
  const int m0 = blockIdx.x * 128, n0 = blockIdx.y * 128;

  f32x4 acc[4][4] = {};

  const int r0 = wave * 32 + (lane >> 2);
  const int bo = (lane & 3) << 4;
  const size_t bhB = (size_t)bh * MATB2;
  const char* aP = (const char*)P  + bhB + (size_t)(m0 + r0) * 448 + bo;
  const char* aV = (const char*)Vt + bhB + (size_t)(n0 + r0) * 448 + bo;
  char* lA = bufA + wave * 2048;
  char* lB = bufB + wave * 2048;

  for (int kc = 0; kc < 7; ++kc) {
    const int ko = kc * 64;
    gload16(lA, aP + ko); gload16(lA + 1024, aP + 16 * 448 + ko);
    gload16(lB, aV + ko); gload16(lB + 1024, aV + 16 * 448 + ko);
    __syncthreads();
    mfma_tiles(bufA, bufB, acc, wr, wc, lane);
    __syncthreads();
  }

  const int q = lane >> 4, c = lane & 15;
  const int b = bh >> 2, h = bh & 3;
#pragma unroll
  for (int i = 0; i < 4; ++i)
#pragma unroll
    for (int j = 0; j < 4; ++j)
#pragma unroll
      for (int r = 0; r < 4; ++r) {
        const int n = m0 + wr * 64 + i * 16 + q * 4 + r;
        const int d = n0 + wc * 64 + j * 16 + c;
        if (n < 196 && d < 196)
          O[(size_t)(b * 196 + n) * KPAD + h * 196 + d] =
              __float2bfloat16(acc[i][j][r]);
      }
}

// -------------------- small prep kernels -----------------------------------
// CP[h][p][kd] = rel_h[h,kd,p/14] + rel_w[h,kd,p%14], hi/lo split, pads zero.
__global__ void build_cp(const float* __restrict__ rh, const float* __restrict__ rw,
                         bf16* __restrict__ CPh, bf16* __restrict__ CPl) {
  const int idx = blockIdx.x * 256 + threadIdx.x;  // < 4*MATE
  if (idx >= 4 * MATE) return;
  const int h = idx / MATE;
  const int rem = idx - h * MATE;
  const int p = rem / PADN, kd = rem - (rem / PADN) * PADN;
  float v = 0.f;
  if (p < 196 && kd < 196) {
    const int gh = p / 14, gw = p - (p / 14) * 14;
    v = rh[(h * 196 + kd) * 14 + gh] + rw[(h * 196 + kd) * 14 + gw];
  }
  const bf16 hv = __float2bfloat16(v);
  CPh[idx] = hv;
  CPl[idx] = __float2bfloat16(v - __bfloat162float(hv));
}

// Zero pad regions of NMAT consecutive 224x224 bf16 mats:
// col-pad rows 0..195 (words 98..111) + row-pad rows 196..223 (full 112 words).
__global__ void zero_pads(uint32_t* __restrict__ base, long nwords) {
  const long g = (long)blockIdx.x * 256 + threadIdx.x;
  if (g >= nwords) return;
  const long mat = g / 5880;
  const int w = (int)(g - mat * 5880);
  int row, off;
  if (w < 2744) { row = w / 14; off = 98 + (w - row * 14); }
  else { const int w2 = w - 2744; row = 196 + w2 / 112; off = w2 - (w2 / 112) * 112; }
  base[mat * 25088 + row * 112 + off] = 0u;
}

// Zero O's K-pad (cols 784..799 bf16 = words 392..399 of each 400-word row).
__global__ void zero_opad(uint32_t* __restrict__ O32, int M) {
  const int t = blockIdx.x * 256 + threadIdx.x;
  if (t >= M * 8) return;
  O32[(size_t)(t >> 3) * 400 + 392 + (t & 7)] = 0u;
}

// fp32 784-row -> bf16 padded-800 row (zero pad), for weights (896 rows).
__global__ void cvt_w_pad(const float* __restrict__ src, bf16* __restrict__ dst) {
  const int t = blockIdx.x * 256 + threadIdx.x;   // < 896*800/4 = 179200
  const int i = t * 4;
  const int row = i / KPAD, col = i - row * KPAD;
  f32x4 v = {0.f, 0.f, 0.f, 0.f};
  if (row < 784 && col < 784) v = *(const f32x4*)(src + (size_t)row * 784 + col);
  bf16x4 o;
  o[0] = (__bf16)v[0]; o[1] = (__bf16)v[1]; o[2] = (__bf16)v[2]; o[3] = (__bf16)v[3];
  *(bf16x4*)(dst + (size_t)row * KPAD + col) = o;
}

// fp32 x chunk -> bf16 padded-800 rows.
__global__ void cvt_x_pad(const float* __restrict__ src, bf16* __restrict__ dst,
                          int M) {
  const long t = (long)blockIdx.x * 256 + threadIdx.x;
  if (t >= (long)M * (KPAD / 4)) return;
  const long i = t * 4;
  const int row = (int)(i / KPAD), col = (int)(i - (long)row * KPAD);
  f32x4 v = {0.f, 0.f, 0.f, 0.f};
  if (col < 784) v = *(const f32x4*)(src + (size_t)row * 784 + col);
  bf16x4 o;
  o[0] = (__bf16)v[0]; o[1] = (__bf16)v[1]; o[2] = (__bf16)v[2]; o[3] = (__bf16)v[3];
  *(bf16x4*)(dst + (size_t)row * KPAD + col) = o;
}

extern "C" void kernel_launch(void* const* d_in, const int* in_sizes, int n_in,
                              void* d_out, int out_size, void* d_ws, size_t ws_size,
                              hipStream_t stream) {
  const float* x  = (const float*)d_in[0];
  const float* Wq = (const float*)d_in[1];
  const float* bq = (const float*)d_in[2];
  const float* Wk = (const float*)d_in[3];
  const float* bk = (const float*)d_in[4];
  const float* Wv = (const float*)d_in[5];
  const float* bv = (const float*)d_in[6];
  const float* Wo = (const float*)d_in[7];
  const float* bo = (const float*)d_in[8];
  const float* rh = (const float*)d_in[9];
  const float* rw = (const float*)d_in[10];
  float* out = (float*)d_out;

  const size_t MAT2B   = (size_t)MATB2;              // 100,352
  const size_t perBmat = 4 * MAT2B;                  // 401,408
  const size_t perBX   = (size_t)196 * KPAD * 2;     // 313,600 (XB / O rows)
  const size_t perBS   = 4 * (size_t)MATE * 4;       // 802,816 (S fp32)
  const size_t perB    = 6 * perBmat + 2 * perBX + perBS;  // 3,838,464
  const size_t WB2     = (size_t)WROWS * KPAD * 2;   // 1,433,600
  const size_t fixed   = 4 * WB2 + 2 * perBmat + 16384;

  int CB = 256;
  while (CB > 32 && (size_t)CB * perB + fixed > ws_size) CB >>= 1;
  if ((size_t)CB * perB + fixed > ws_size) return;   // ws hopeless

  char* ws = (char*)d_ws;
  const size_t bufSz = (size_t)CB * perBmat;
  bf16*  Qb  = (bf16*)(ws);
  bf16*  Kb  = (bf16*)(ws + bufSz);
  bf16*  Qth = (bf16*)(ws + 2 * bufSz);
  bf16*  Qtl = (bf16*)(ws + 3 * bufSz);
  bf16*  Vtb = (bf16*)(ws + 4 * bufSz);
  bf16*  Pb  = (bf16*)(ws + 5 * bufSz);
  bf16*  XB  = (bf16*)(ws + 6 * bufSz);
  bf16*  Ob  = (bf16*)(ws + 6 * bufSz + (size_t)CB * perBX);
  float* S   = (float*)(ws + 6 * bufSz + (size_t)CB * 2 * perBX);
  char*  fx  = ws + 6 * bufSz + (size_t)CB * (2 * perBX + perBS);
  bf16* WqB = (bf16*)(fx);
  bf16* WkB = (bf16*)(fx + WB2);
  bf16* WvB = (bf16*)(fx + 2 * WB2);
  bf16* WoB = (bf16*)(fx + 3 * WB2);
  bf16* CPh = (bf16*)(fx + 4 * WB2);
  bf16* CPl = (bf16*)(fx + 4 * WB2 + perBmat);

  // One-time prep (ws is re-poisoned by the harness every call).
  const long zw = (long)CB * 20 * 5880;              // Q,K,Qth,Qtl,Vt pads
  zero_pads<<<(int)((zw + 255) / 256), 256, 0, stream>>>((uint32_t*)ws, zw);
  const int M = CB * 196;
  zero_opad<<<(M * 8 + 255) / 256, 256, 0, stream>>>((uint32_t*)Ob, M);
  build_cp<<<(4 * MATE + 255) / 256, 256, 0, stream>>>(rh, rw, CPh, CPl);
  cvt_w_pad<<<700, 256, 0, stream>>>(Wq, WqB);
  cvt_w_pad<<<700, 256, 0, stream>>>(Wk, WkB);
  cvt_w_pad<<<700, 256, 0, stream>>>(Wv, WvB);
  cvt_w_pad<<<700, 256, 0, stream>>>(Wo, WoB);

  const int gm = M / 128;                            // M % 128 == 0 (CB >= 32)
  for (int c0 = 0; c0 < 256; c0 += CB) {
    const long xt = (long)M * (KPAD / 4);
    cvt_x_pad<<<(int)((xt + 255) / 256), 256, 0, stream>>>(
        x + (size_t)c0 * 196 * 784, XB, M);

    gemm_proj<0><<<dim3(gm, 7), 256, 0, stream>>>(XB, WqB, bq, Qb, nullptr, nullptr, M);
    gemm_proj<1><<<dim3(gm, 7), 256, 0, stream>>>(XB, WkB, bk, Kb, nullptr, nullptr, M);
    gemm_proj<2><<<dim3(7, gm), 256, 0, stream>>>(WqB, XB, bq, Qth, Qtl, nullptr, M);
    gemm_proj<3><<<dim3(7, gm), 256, 0, stream>>>(WvB, XB, bv, Vtb, nullptr, nullptr, M);

    attn_score<<<dim3(2, 2, CB * 4), 256, 0, stream>>>(Qb, Kb, CPh, CPl, Qth, Qtl, S);
    softmax_k<<<dim3(56, CB * 4), 256, 0, stream>>>(S, Pb);
    attn_pv<<<dim3(2, 2, CB * 4), 256, 0, stream>>>(Pb, Vtb, Ob);

    gemm_proj<4><<<dim3(gm, 7), 256, 0, stream>>>(Ob, WoB, bo, nullptr, nullptr,
                                                  out + (size_t)c0 * 196 * 784, M);
  }
}